// Round 11
// baseline (136.687 us; speedup 1.0000x reference)
//
#include <hip/hip_runtime.h>
#include <hip/hip_fp8.h>
#include <math.h>

#define NROW 4096
#define FDIM 512
#define MARGIN 1.0f

typedef __attribute__((ext_vector_type(8))) short short8;
typedef __attribute__((ext_vector_type(4))) float floatx4;

__device__ inline float h2f(unsigned short u) {
    _Float16 h; __builtin_memcpy(&h, &u, 2); return (float)h;
}
__device__ inline unsigned short f2h(float f) {
    _Float16 h = (_Float16)f; unsigned short u; __builtin_memcpy(&u, &h, 2); return u;
}
__device__ inline unsigned char f2fp8(float x) {
    __hip_fp8_e4m3 v(x);            // OCP e4m3fn, RNE+sat
    return v.__x;
}
__device__ inline void glds16(const unsigned char* g, unsigned char* l) {
    __builtin_amdgcn_global_load_lds(
        (const __attribute__((address_space(1))) unsigned int*)g,
        (__attribute__((address_space(3))) unsigned int*)l, 16, 0, 0);
}

// ---------------------------------------------------------------------------
// Fused prep: fp8 convert + fp32 row norms + zero rns/loss. One wave per row;
// each lane owns 8 consecutive elements (2 float4 loads -> 8 fp8 bytes).
// ---------------------------------------------------------------------------
__global__ __launch_bounds__(64) void prep_kernel(
    const float* __restrict__ a, const float* __restrict__ b,
    unsigned char* __restrict__ a8, unsigned char* __restrict__ b8,
    float* __restrict__ na, float* __restrict__ nb,
    float* __restrict__ rns, float* __restrict__ loss) {
    int row  = blockIdx.x;
    int lane = threadIdx.x;
    const float4* a4 = (const float4*)(a + (size_t)row * FDIM);
    const float4* b4 = (const float4*)(b + (size_t)row * FDIM);
    float4 va0 = a4[lane * 2], va1 = a4[lane * 2 + 1];
    float4 vb0 = b4[lane * 2], vb1 = b4[lane * 2 + 1];
    float sa = va0.x*va0.x + va0.y*va0.y + va0.z*va0.z + va0.w*va0.w
             + va1.x*va1.x + va1.y*va1.y + va1.z*va1.z + va1.w*va1.w;
    float sb = vb0.x*vb0.x + vb0.y*vb0.y + vb0.z*vb0.z + vb0.w*vb0.w
             + vb1.x*vb1.x + vb1.y*vb1.y + vb1.z*vb1.z + vb1.w*vb1.w;
    union { unsigned char c[8]; unsigned long long u; } pa, pb;
    pa.c[0]=f2fp8(va0.x); pa.c[1]=f2fp8(va0.y); pa.c[2]=f2fp8(va0.z); pa.c[3]=f2fp8(va0.w);
    pa.c[4]=f2fp8(va1.x); pa.c[5]=f2fp8(va1.y); pa.c[6]=f2fp8(va1.z); pa.c[7]=f2fp8(va1.w);
    pb.c[0]=f2fp8(vb0.x); pb.c[1]=f2fp8(vb0.y); pb.c[2]=f2fp8(vb0.z); pb.c[3]=f2fp8(vb0.w);
    pb.c[4]=f2fp8(vb1.x); pb.c[5]=f2fp8(vb1.y); pb.c[6]=f2fp8(vb1.z); pb.c[7]=f2fp8(vb1.w);
    ((unsigned long long*)(a8 + (size_t)row * FDIM))[lane] = pa.u;
    ((unsigned long long*)(b8 + (size_t)row * FDIM))[lane] = pb.u;
    #pragma unroll
    for (int o = 32; o > 0; o >>= 1) {
        sa += __shfl_down(sa, o);
        sb += __shfl_down(sb, o);
    }
    if (lane == 0) {
        na[row] = sa;
        nb[row] = sb;
        rns[row] = 0.f;
        if (row == 0) loss[0] = 0.f;
    }
}

// ---------------------------------------------------------------------------
// fp8 MFMA pass: 128x128 tile of S = b @ a^T, BK=32 double-buffered,
// 4 waves 2x2, mfma_f32_16x16x32_fp8_fp8 (bf16 rate, half the bytes).
// D stored in C-FRAGMENT ORDER (coalesced 16B stores, no LDS transpose).
// MODE 0: phase1 (negsum) + store D fragments
// MODE 1: phase1 only                   (fallback when ws too small)
// MODE 2: phase2 recompute + hinge^2    (fallback)
// ---------------------------------------------------------------------------
template <int MODE>
__global__ __launch_bounds__(256) void pass_mfma(
    const unsigned char* __restrict__ a8, const unsigned char* __restrict__ b8,
    const int* __restrict__ labels,
    const float* __restrict__ na, const float* __restrict__ nb,
    float* __restrict__ rns, unsigned short* __restrict__ Dws,
    float* __restrict__ loss_sum)
{
    // 16 KB: 2 x (As 4KB + Bs 4KB) double buffer. A tile = 128 rows x 32 B.
    __shared__ __align__(16) unsigned char arena[16384];
    __shared__ int   li_s[128], lj_s[128];
    __shared__ float nb_s[128], na_s[128], rbi_s[128], rbj_s[128];

    const int t    = threadIdx.x;
    const int lane = t & 63;
    const int w    = t >> 6;
    const int wi   = w >> 1, wj = w & 1;
    // supertile swizzle: 8x8 blocks per supertile for XCD/L2 locality
    const int bid  = blockIdx.x;
    const int sup  = bid >> 6, loc = bid & 63;
    const int by   = ((sup >> 2) << 3) | (loc >> 3);
    const int bx   = ((sup & 3) << 3) | (loc & 7);
    const int ti   = by * 128;           // b-row (i) origin
    const int tj   = bx * 128;           // a-row (j) origin
    const int lr   = lane & 15;
    const int lq   = lane >> 4;

    floatx4 acc[4][4];
    #pragma unroll
    for (int i = 0; i < 4; ++i)
        #pragma unroll
        for (int j = 0; j < 4; ++j)
            acc[i][j] = (floatx4){0.f, 0.f, 0.f, 0.f};

    if (t < 128) {
        li_s[t] = labels[ti + t];
        nb_s[t] = nb[ti + t];
        if (MODE == 2) rbi_s[t] = rns[ti + t];
    } else {
        int u = t - 128;
        lj_s[u] = labels[tj + u];
        na_s[u] = na[tj + u];
        if (MODE == 2) rbj_s[u] = rns[tj + u];
    }

    // stage one BK=32 tile pair (512 x 16B chunks: 256 A-side + 256 B-side)
    auto stage = [&](int kk, int buf) {
        unsigned char* As = arena + buf * 8192;
        unsigned char* Bs = As + 4096;
        #pragma unroll
        for (int l = 0; l < 2; ++l) {
            int c = t + l * 256;              // 0..511
            if (c < 256) {
                int row = c >> 1, q = c & 1;
                glds16(a8 + (size_t)(tj + row) * FDIM + kk + q * 16, As + c * 16);
            } else {
                int c2 = c - 256;
                int row = c2 >> 1, q = c2 & 1;
                glds16(b8 + (size_t)(ti + row) * FDIM + kk + q * 16, Bs + c2 * 16);
            }
        }
    };

    stage(0, 0);
    __syncthreads();

    #pragma unroll
    for (int it = 0; it < FDIM / 32; ++it) {
        if (it < FDIM / 32 - 1) stage((it + 1) * 32, (it + 1) & 1);

        const unsigned char* As = arena + (it & 1) * 8192;
        const unsigned char* Bs = As + 4096;
        long af[4], bf[4];
        #pragma unroll
        for (int ri = 0; ri < 4; ++ri)
            af[ri] = *(const long*)&Bs[(wi * 64 + ri * 16 + lr) * 32 + lq * 8];
        #pragma unroll
        for (int rj = 0; rj < 4; ++rj)
            bf[rj] = *(const long*)&As[(wj * 64 + rj * 16 + lr) * 32 + lq * 8];
        #pragma unroll
        for (int ri = 0; ri < 4; ++ri)
            #pragma unroll
            for (int rj = 0; rj < 4; ++rj)
                acc[ri][rj] = __builtin_amdgcn_mfma_f32_16x16x32_fp8_fp8(
                    af[ri], bf[rj], acc[ri][rj], 0, 0, 0);
        __syncthreads();
    }

    if (MODE == 0 || MODE == 1) {
        // phase-1 epilogue: C/D layout col = lane&15, row = quad*4 + reg
        unsigned short* dblk = Dws + (size_t)bid * 16384;
        #pragma unroll
        for (int ri = 0; ri < 4; ++ri) {
            float rs[4] = {0.f, 0.f, 0.f, 0.f};
            unsigned short dloc[16];
            #pragma unroll
            for (int rj = 0; rj < 4; ++rj) {
                int   jl  = wj * 64 + rj * 16 + lr;
                float naj = na_s[jl];
                int   ljv = lj_s[jl];
                #pragma unroll
                for (int r = 0; r < 4; ++r) {
                    int   il  = wi * 64 + ri * 16 + lq * 4 + r;
                    float dsq = nb_s[il] + naj - 2.f * acc[ri][rj][r];
                    float D   = sqrtf(fmaxf(dsq, 0.f));
                    if (li_s[il] != ljv) rs[r] += __expf(MARGIN - D);
                    if (MODE == 0) dloc[rj * 4 + r] = f2h(D);
                }
            }
            #pragma unroll
            for (int r = 0; r < 4; ++r) {
                #pragma unroll
                for (int o = 8; o > 0; o >>= 1) rs[r] += __shfl_down(rs[r], o, 16);
            }
            if (lr == 0) {
                #pragma unroll
                for (int r = 0; r < 4; ++r)
                    atomicAdd(&rns[ti + wi * 64 + ri * 16 + lq * 4 + r], rs[r]);
            }
            if (MODE == 0) {
                *(short8*)&dblk[(ri * 2 + 0) * 2048 + t * 8] = *(short8*)&dloc[0];
                *(short8*)&dblk[(ri * 2 + 1) * 2048 + t * 8] = *(short8*)&dloc[8];
            }
        }
    } else {
        // phase-2 recompute epilogue
        float local = 0.f;
        #pragma unroll
        for (int ri = 0; ri < 4; ++ri)
            #pragma unroll
            for (int rj = 0; rj < 4; ++rj) {
                int jl  = wj * 64 + rj * 16 + lr;
                int ljv = lj_s[jl];
                float naj = na_s[jl], rbj = rbj_s[jl];
                #pragma unroll
                for (int r = 0; r < 4; ++r) {
                    int il = wi * 64 + ri * 16 + lq * 4 + r;
                    int i  = ti + il, j = tj + jl;
                    if (li_s[il] == ljv && i != j) {
                        float dsq = nb_s[il] + naj - 2.f * acc[ri][rj][r];
                        float D   = sqrtf(fmaxf(dsq, 0.f));
                        float J   = __logf(rbi_s[il] + rbj) + D;
                        float h   = fmaxf(J, 0.f);
                        local += h * h;
                    }
                }
            }
        #pragma unroll
        for (int o = 32; o > 0; o >>= 1) local += __shfl_down(local, o);
        __shared__ float part[4];
        if (lane == 0) part[w] = local;
        __syncthreads();
        if (t == 0) atomicAdd(loss_sum, part[0] + part[1] + part[2] + part[3]);
    }
}

// ---------------------------------------------------------------------------
// Phase-2 sweep: one block per GEMM tile; reads D fragments back in the same
// C-fragment order (coalesced 16B), labels/rns staged in 2KB LDS.
// ---------------------------------------------------------------------------
__global__ __launch_bounds__(256) void pass2_sweep(
    const unsigned short* __restrict__ Dws, const int* __restrict__ labels,
    const float* __restrict__ rns, float* __restrict__ loss_sum)
{
    __shared__ int   lab_i[128], lab_j[128];
    __shared__ float rb_i[128], rb_j[128];

    const int t    = threadIdx.x;
    const int lane = t & 63;
    const int w    = t >> 6;
    const int wi   = w >> 1, wj = w & 1;
    const int bid  = blockIdx.x;
    const int sup  = bid >> 6, loc = bid & 63;
    const int by   = ((sup >> 2) << 3) | (loc >> 3);
    const int bx   = ((sup & 3) << 3) | (loc & 7);
    const int ti   = by * 128;
    const int tj   = bx * 128;
    const int lr   = lane & 15;
    const int lq   = lane >> 4;

    if (t < 128) {
        lab_i[t] = labels[ti + t];
        rb_i[t]  = rns[ti + t];
    } else {
        int u = t - 128;
        lab_j[u] = labels[tj + u];
        rb_j[u]  = rns[tj + u];
    }
    __syncthreads();

    const unsigned short* dblk = Dws + (size_t)bid * 16384;
    float local = 0.f;
    #pragma unroll
    for (int ri = 0; ri < 4; ++ri) {
        short8 d0 = *(const short8*)&dblk[(ri * 2 + 0) * 2048 + t * 8];
        short8 d1 = *(const short8*)&dblk[(ri * 2 + 1) * 2048 + t * 8];
        #pragma unroll
        for (int rj = 0; rj < 4; ++rj) {
            int jl  = wj * 64 + rj * 16 + lr;
            int ljv = lab_j[jl];
            #pragma unroll
            for (int r = 0; r < 4; ++r) {
                int il = wi * 64 + ri * 16 + lq * 4 + r;
                if (lab_i[il] == ljv && (ti + il) != (tj + jl)) {
                    unsigned short du = (rj < 2)
                        ? (unsigned short)d0[rj * 4 + r]
                        : (unsigned short)d1[(rj - 2) * 4 + r];
                    float J = __logf(rb_i[il] + rb_j[jl]) + h2f(du);
                    float h = fmaxf(J, 0.f);
                    local += h * h;
                }
            }
        }
    }
    #pragma unroll
    for (int o = 32; o > 0; o >>= 1) local += __shfl_down(local, o);
    __shared__ float part[4];
    if (lane == 0) part[w] = local;
    __syncthreads();
    if (t == 0) atomicAdd(loss_sum, part[0] + part[1] + part[2] + part[3]);
}

// ---------------------------------------------------------------------------
__global__ __launch_bounds__(256) void finalize_kernel(const int* __restrict__ labels,
                                                       const float* __restrict__ loss_sum,
                                                       float* __restrict__ out) {
    __shared__ int hist[16];
    int t = threadIdx.x;
    if (t < 16) hist[t] = 0;
    __syncthreads();
    for (int i = t; i < NROW; i += 256) atomicAdd(&hist[labels[i] & 15], 1);
    __syncthreads();
    if (t == 0) {
        long long np = 0;
        for (int c = 0; c < 16; ++c) np += (long long)hist[c] * (long long)(hist[c] - 1);
        out[0] = loss_sum[0] / (2.0f * (float)np);
    }
}

// ---------------------------------------------------------------------------
extern "C" void kernel_launch(void* const* d_in, const int* in_sizes, int n_in,
                              void* d_out, int out_size, void* d_ws, size_t ws_size,
                              hipStream_t stream) {
    const float* a      = (const float*)d_in[0];
    const float* b      = (const float*)d_in[1];
    const int*   labels = (const int*)d_in[2];
    float* out = (float*)d_out;

    // ws: a8(2MB) | b8(2MB) | na,nb,rns,loss(+pad) | Dws(32MB fp16)
    unsigned char* a8 = (unsigned char*)d_ws;
    unsigned char* b8 = a8 + (size_t)NROW * FDIM;
    float* fws  = (float*)(b8 + (size_t)NROW * FDIM);
    float* na   = fws;
    float* nb   = fws + NROW;
    float* rns  = fws + 2 * NROW;
    float* loss = fws + 3 * NROW;
    unsigned short* Dws = (unsigned short*)(fws + 3 * NROW + 4);   // 16B aligned

    size_t need = ((char*)Dws - (char*)d_ws) + (size_t)NROW * NROW * 2;

    prep_kernel<<<NROW, 64, 0, stream>>>(a, b, a8, b8, na, nb, rns, loss);

    dim3 grid((NROW / 128) * (NROW / 128));   // 1024 blocks
    if (ws_size >= need) {
        pass_mfma<0><<<grid, 256, 0, stream>>>(a8, b8, labels, na, nb, rns, Dws, loss);
        pass2_sweep<<<grid, 256, 0, stream>>>(Dws, labels, rns, loss);
    } else {
        pass_mfma<1><<<grid, 256, 0, stream>>>(a8, b8, labels, na, nb, rns, Dws, loss);
        pass_mfma<2><<<grid, 256, 0, stream>>>(a8, b8, labels, na, nb, rns, Dws, loss);
    }

    finalize_kernel<<<1, 256, 0, stream>>>(labels, loss, out);
}